// Round 7
// baseline (188.287 us; speedup 1.0000x reference)
//
#include <hip/hip_runtime.h>

#define LL 512
#define BB 32
#define TT 48
#define GROW 5.0f
#define ENEG 6.737946999085467e-03f   // exp(-GROW)
#define NSLOT (LL + 4)                // 4 pad slots so prefetch never clamps

typedef _Float16 f16x2 __attribute__((ext_vector_type(2)));
typedef _Float16 f16x4 __attribute__((ext_vector_type(4)));
typedef float    f32x4 __attribute__((ext_vector_type(4)));

__device__ __forceinline__ f16x4 mk4(unsigned lo, unsigned hi) {
  unsigned long long uu = (unsigned long long)lo | ((unsigned long long)hi << 32);
  return __builtin_bit_cast(f16x4, uu);
}
__device__ __forceinline__ f16x2 pkrtz(float a, float b) {
  return __builtin_bit_cast(f16x2, __builtin_amdgcn_cvt_pkrtz(a, b));
}

// ---------------- fused prep (blocks 0..515) + numerator (blocks 516..547) ----------------
// prep: stage u = exp(0.5E) packed f16 in scan's per-lane layout; slots 512-515 dup slot 511.
__global__ __launch_bounds__(128, 1)
void prep_kernel(const float* __restrict__ E, const int* __restrict__ tags,
                 const int* __restrict__ lens, const int* __restrict__ mask,
                 const float* __restrict__ st, const float* __restrict__ et,
                 const float* __restrict__ tr, float* __restrict__ ws_,
                 float* __restrict__ out)
{
  const int bid = blockIdx.x;
  const int tid = threadIdx.x;
  char* ws = (char*)ws_;

  if (bid < NSLOT) {
    const int j = (bid < LL) ? bid : (LL - 1);
    const int w = tid >> 6, l = tid & 63;
    const int g = l >> 4, b = w * 16 + (l & 15);
    __shared__ float Et[BB * TT];
    for (int i = tid; i < BB * TT; i += 128) Et[i] = E[(size_t)j * BB * TT + i];
    __syncthreads();
    unsigned dws[6];
    #pragma unroll
    for (int blk = 0; blk < 3; ++blk)
      #pragma unroll
      for (int h = 0; h < 2; ++h) {
        const int t0 = 16 * blk + 4 * g + 2 * h;
        dws[2 * blk + h] = __builtin_bit_cast(unsigned,
            pkrtz(__expf(0.5f * Et[b * TT + t0]), __expf(0.5f * Et[b * TT + t0 + 1])));
      }
    uint4 s0 = {dws[0], dws[1], dws[2], dws[3]};
    uint4 s1 = {dws[4], dws[5], __float_as_uint(mask[j * BB + b] ? 1.f : 0.f), 0u};
    uint4* dst = (uint4*)(ws + (size_t)((bid * 2 + w) * 64 + l) * 32);
    dst[0] = s0; dst[1] = s1;
    return;
  }

  // ---- numerator: one block per batch, wave 0 only ----
  if (tid >= 64) return;
  const int b = bid - NSLOT;
  const int s = tid;
  const int lenv = lens[s * BB + b];
  int pre = lenv;
  #pragma unroll
  for (int off = 1; off < 64; off <<= 1) {
    int y = __shfl_up(pre, off, 64);
    if (s >= off) pre += y;
  }
  int ms = 0;
  #pragma unroll
  for (int kk = 0; kk < LL / 64; ++kk) ms += mask[(s + 64 * kk) * BB + b];
  #pragma unroll
  for (int off = 32; off; off >>= 1) ms += __shfl_xor(ms, off, 64);
  const int max_idx = (ms < LL - 1) ? ms : (LL - 1);
  float term;
  if (s == 0) {
    const int tag0 = tags[b];
    int i1 = lenv - 1; if (i1 < 0) i1 = 0; if (i1 > LL - 1) i1 = LL - 1;
    const float se = 0.5f * (E[b * TT + tag0] + E[(i1 * BB + b) * TT + tag0]);
    int send = ms - 1; if (send < 0) send = 0; if (send > LL - 1) send = LL - 1;
    term = st[tag0] + se + et[tags[send * BB + b]];
  } else {
    int startp = pre - lenv;
    if (startp > max_idx) startp = max_idx;
    int endp1 = startp + lenv - 1; if (endp1 > LL - 1) endp1 = LL - 1;
    int sm1 = startp - 1; if (sm1 < 0) sm1 = 0;
    const int  stg = tags[startp * BB + b];
    const int  ptg = tags[sm1 * BB + b];
    const int  etg = tags[endp1 * BB + b];
    const float m  = (float)mask[startp * BB + b];
    const float se = 0.5f * (E[(startp * BB + b) * TT + stg] + E[(endp1 * BB + b) * TT + stg]);
    term = (se + tr[ptg * TT + etg]) * m;
  }
  #pragma unroll
  for (int off = 32; off; off >>= 1) term += __shfl_xor(term, off, 64);
  if (s == 0) atomicAdd(out, term);
}

// ---------------- scan: 1 wave per 16 batches; MFMA recurrence + MFMA broadcast ----------------
__global__ __launch_bounds__(64, 1)
void scan_kernel(const float* __restrict__ tr, const float* __restrict__ st,
                 const float* __restrict__ et, const float* __restrict__ E,
                 const float* __restrict__ ws_, float* __restrict__ out)
{
  const int w = blockIdx.x;      // 0,1 -> batches w*16 .. w*16+15
  const int l = threadIdx.x;
  const int g = l >> 4;
  const int b = w * 16 + (l & 15);
  const char* ws = (const char*)ws_;

  // A = W^T fragments: lane holds A[m=16mb+(l&15)][k=16kb+4g+i]
  f16x4 A[3][3];
  #pragma unroll
  for (int mb = 0; mb < 3; ++mb)
    #pragma unroll
    for (int kb = 0; kb < 3; ++kb) {
      f16x4 a;
      #pragma unroll
      for (int i = 0; i < 4; ++i)
        a[i] = (_Float16)__expf(tr[(16 * kb + 4 * g + i) * TT + 16 * mb + (l & 15)]);
      unsigned long long aa = __builtin_bit_cast(unsigned long long, a);
      asm volatile("" : "+v"(aa));   // pin (r2 lesson)
      A[mb][kb] = __builtin_bit_cast(f16x4, aa);
    }
  // A_sel[m][k] = (k==0): broadcast matrix -> D_b[m][n] = B[0][n] = v[tag0][batch n]
  f16x4 Asel = {(_Float16)0.f, (_Float16)0.f, (_Float16)0.f, (_Float16)0.f};
  if (g == 0) Asel[0] = (_Float16)1.f;
  { unsigned long long aa = __builtin_bit_cast(unsigned long long, Asel);
    asm volatile("" : "+v"(aa));
    Asel = __builtin_bit_cast(f16x4, aa); }

  // init state j=0 (computed in-kernel; scan uses no LDS at all)
  const float M0 = st[0] + E[b * TT + 0];
  unsigned vd[6]; f16x2 C[6];
  #pragma unroll
  for (int blk = 0; blk < 3; ++blk)
    #pragma unroll
    for (int h = 0; h < 2; ++h) {
      const int t0 = 16 * blk + 4 * g + 2 * h;
      const float ea = E[b * TT + t0], eb = E[b * TT + t0 + 1];
      C[2 * blk + h] = pkrtz(__expf(st[t0] - M0 + 0.5f * ea),
                             __expf(st[t0 + 1] - M0 + 0.5f * eb));
      vd[2 * blk + h] = __builtin_bit_cast(unsigned,
          pkrtz(__expf(st[t0] - M0 + ea), __expf(st[t0 + 1] - M0 + eb)));
    }
  float lsum = 0.f;

  // u prefetch: ring p holds slot j (j mod 4 == p); slot stride 4096 B
  const char* Ubase = ws + (size_t)(w * 64 + l) * 32;
  uint4 ua[4], ub[4];
  const char* up[4];
  #pragma unroll
  for (int p = 0; p < 4; ++p) {
    const int j0 = (p == 0) ? 4 : p;
    ua[p] = *(const uint4*)(Ubase + (size_t)j0 * 4096);
    ub[p] = *(const uint4*)(Ubase + (size_t)j0 * 4096 + 16);
    up[p] = Ubase + (size_t)(j0 + 4) * 4096;
  }

  const f32x4 zero4 = {0.f, 0.f, 0.f, 0.f};

  auto step = [&](int p) {
    const f16x4 B0 = mk4(vd[0], vd[1]);
    const f16x4 B1 = mk4(vd[2], vd[3]);
    const f16x4 B2 = mk4(vd[4], vd[5]);
    // broadcast first (feeds eg), then the 3-chained matvec frags (MFMA pipe)
    f32x4 Db = __builtin_amdgcn_mfma_f32_16x16x16f16(Asel, B0, zero4, 0, 0, 0);
    f32x4 D0 = __builtin_amdgcn_mfma_f32_16x16x16f16(A[0][0], B0, zero4, 0, 0, 0);
    f32x4 D1 = __builtin_amdgcn_mfma_f32_16x16x16f16(A[1][0], B0, zero4, 0, 0, 0);
    f32x4 D2 = __builtin_amdgcn_mfma_f32_16x16x16f16(A[2][0], B0, zero4, 0, 0, 0);
    D0 = __builtin_amdgcn_mfma_f32_16x16x16f16(A[0][1], B1, D0, 0, 0, 0);
    D1 = __builtin_amdgcn_mfma_f32_16x16x16f16(A[1][1], B1, D1, 0, 0, 0);
    D2 = __builtin_amdgcn_mfma_f32_16x16x16f16(A[2][1], B1, D2, 0, 0, 0);
    D0 = __builtin_amdgcn_mfma_f32_16x16x16f16(A[0][2], B2, D0, 0, 0, 0);
    D1 = __builtin_amdgcn_mfma_f32_16x16x16f16(A[1][2], B2, D1, 0, 0, 0);
    D2 = __builtin_amdgcn_mfma_f32_16x16x16f16(A[2][2], B2, D2, 0, 0, 0);

    const uint4 uA = ua[p], uB = ub[p];
    ua[p] = *(const uint4*)up[p];
    ub[p] = *(const uint4*)(up[p] + 16);
    up[p] += 4 * 4096;

    const float v0bc = Db[0];                           // in-lane normalizer, all lanes
    const float eg = __builtin_amdgcn_rcpf(v0bc) * ENEG;
    lsum += __logf(v0bc);
    const f16x2 egpk = pkrtz(eg, eg);

    const float mf = __uint_as_float(uB.z);
    const unsigned udw[6] = {uA.x, uA.y, uA.z, uA.w, uB.x, uB.y};
    const float Dv[12] = {D0[0], D0[1], D0[2], D0[3],
                          D1[0], D1[1], D1[2], D1[3],
                          D2[0], D2[1], D2[2], D2[3]};

    if (__builtin_expect(__ballot(mf == 0.f) == 0, 1)) {
      // fast path (mask all-ones): 5 packed ops per f16x2
      #pragma unroll
      for (int d6 = 0; d6 < 6; ++d6) {
        const f16x2 pa = pkrtz(Dv[2 * d6], Dv[2 * d6 + 1]);
        const f16x2 ud = __builtin_bit_cast(f16x2, udw[d6]);
        const f16x2 Cn = (C[d6] + pa * ud) * egpk;
        C[d6] = Cn;
        vd[d6] = __builtin_bit_cast(unsigned, ud * Cn);
      }
    } else {
      // rare masked path: hold alpha (and C), rescaled
      #pragma unroll
      for (int d6 = 0; d6 < 6; ++d6) {
        const f16x2 pa = pkrtz(Dv[2 * d6], Dv[2 * d6 + 1]);
        const f16x2 ud = __builtin_bit_cast(f16x2, udw[d6]);
        const f16x2 Cn = (C[d6] + pa * ud) * egpk;
        const f16x2 Ch = C[d6] * egpk;
        const f16x2 vn = ud * Cn;
        const f16x2 vh = __builtin_bit_cast(f16x2, vd[d6]) * egpk;
        const bool keep = (mf > 0.f);
        C[d6] = keep ? Cn : Ch;
        vd[d6] = __builtin_bit_cast(unsigned, keep ? vn : vh);
      }
    }
  };

  // steps j = 1 .. 511 (p = j & 3); refills reach slot 515 (padded)
  for (int c = 0; c < 127; ++c) {
    step(1); step(2); step(3); step(0);
  }
  step(1); step(2); step(3);

  // epilogue: denom_b = M0 + 511*GROW + lsum + log(sum_t v[t,b]*exp(et[t]))
  float s = 0.f;
  #pragma unroll
  for (int blk = 0; blk < 3; ++blk)
    #pragma unroll
    for (int h = 0; h < 2; ++h) {
      const int t0 = 16 * blk + 4 * g + 2 * h;
      const f16x2 vp = __builtin_bit_cast(f16x2, vd[2 * blk + h]);
      s += (float)vp.x * __expf(et[t0]) + (float)vp.y * __expf(et[t0 + 1]);
    }
  s += __shfl_xor(s, 16, 64);
  s += __shfl_xor(s, 32, 64);
  float den = (M0 + 511.0f * GROW + lsum) + __logf(s);
  #pragma unroll
  for (int off = 1; off < 16; off <<= 1) den += __shfl_xor(den, off, 64);
  if (l == 0) atomicAdd(out, -den);
}

extern "C" void kernel_launch(void* const* d_in, const int* in_sizes, int n_in,
                              void* d_out, int out_size, void* d_ws, size_t ws_size,
                              hipStream_t stream) {
  (void)in_sizes; (void)n_in; (void)ws_size;
  const float* E    = (const float*)d_in[0];
  const int*   tags = (const int*)d_in[1];
  const int*   lens = (const int*)d_in[2];
  const int*   mask = (const int*)d_in[3];
  const float* st   = (const float*)d_in[4];
  const float* et   = (const float*)d_in[5];
  const float* tr   = (const float*)d_in[6];
  float* out = (float*)d_out;
  (void)hipMemsetAsync(out, 0, out_size * sizeof(float), stream);
  prep_kernel<<<dim3(NSLOT + BB), dim3(128), 0, stream>>>(E, tags, lens, mask, st, et, tr,
                                                          (float*)d_ws, out);
  scan_kernel<<<dim3(2), dim3(64), 0, stream>>>(tr, st, et, E, (const float*)d_ws, out);
}

// Round 8
// 182.546 us; speedup vs baseline: 1.0314x; 1.0314x over previous
//
#include <hip/hip_runtime.h>

#define LL 512
#define BB 32
#define TT 48
#define GROW 5.0f
#define ENEG 6.737946999085467e-03f   // exp(-GROW)
#define NSLOT (LL + 8)                // 8 pad slots: depth-8 prefetch never clamps

typedef _Float16 f16x2 __attribute__((ext_vector_type(2)));
typedef _Float16 f16x4 __attribute__((ext_vector_type(4)));
typedef float    f32x4 __attribute__((ext_vector_type(4)));

__device__ __forceinline__ f16x4 mk4(unsigned lo, unsigned hi) {
  unsigned long long uu = (unsigned long long)lo | ((unsigned long long)hi << 32);
  return __builtin_bit_cast(f16x4, uu);
}
__device__ __forceinline__ f16x2 pkrtz(float a, float b) {
  return __builtin_bit_cast(f16x2, __builtin_amdgcn_cvt_pkrtz(a, b));
}

// ---------------- fused prep (blocks 0..NSLOT-1) + numerator (last BB blocks) ----------------
__global__ __launch_bounds__(128, 1)
void prep_kernel(const float* __restrict__ E, const int* __restrict__ tags,
                 const int* __restrict__ lens, const int* __restrict__ mask,
                 const float* __restrict__ st, const float* __restrict__ et,
                 const float* __restrict__ tr, float* __restrict__ ws_,
                 float* __restrict__ out)
{
  const int bid = blockIdx.x;
  const int tid = threadIdx.x;
  char* ws = (char*)ws_;

  if (bid < NSLOT) {
    const int j = (bid < LL) ? bid : (LL - 1);
    const int w = tid >> 6, l = tid & 63;
    const int g = l >> 4, b = w * 16 + (l & 15);
    __shared__ float Et[BB * TT];
    for (int i = tid; i < BB * TT; i += 128) Et[i] = E[(size_t)j * BB * TT + i];
    __syncthreads();
    unsigned dws[6];
    #pragma unroll
    for (int blk = 0; blk < 3; ++blk)
      #pragma unroll
      for (int h = 0; h < 2; ++h) {
        const int t0 = 16 * blk + 4 * g + 2 * h;
        dws[2 * blk + h] = __builtin_bit_cast(unsigned,
            pkrtz(__expf(0.5f * Et[b * TT + t0]), __expf(0.5f * Et[b * TT + t0 + 1])));
      }
    uint4 s0 = {dws[0], dws[1], dws[2], dws[3]};
    uint4 s1 = {dws[4], dws[5], __float_as_uint(mask[j * BB + b] ? 1.f : 0.f), 0u};
    uint4* dst = (uint4*)(ws + (size_t)((bid * 2 + w) * 64 + l) * 32);
    dst[0] = s0; dst[1] = s1;
    return;
  }

  // ---- numerator: one block per batch, wave 0 only ----
  if (tid >= 64) return;
  const int b = bid - NSLOT;
  const int s = tid;
  const int lenv = lens[s * BB + b];
  int pre = lenv;
  #pragma unroll
  for (int off = 1; off < 64; off <<= 1) {
    int y = __shfl_up(pre, off, 64);
    if (s >= off) pre += y;
  }
  int ms = 0;
  #pragma unroll
  for (int kk = 0; kk < LL / 64; ++kk) ms += mask[(s + 64 * kk) * BB + b];
  #pragma unroll
  for (int off = 32; off; off >>= 1) ms += __shfl_xor(ms, off, 64);
  const int max_idx = (ms < LL - 1) ? ms : (LL - 1);
  float term;
  if (s == 0) {
    const int tag0 = tags[b];
    int i1 = lenv - 1; if (i1 < 0) i1 = 0; if (i1 > LL - 1) i1 = LL - 1;
    const float se = 0.5f * (E[b * TT + tag0] + E[(i1 * BB + b) * TT + tag0]);
    int send = ms - 1; if (send < 0) send = 0; if (send > LL - 1) send = LL - 1;
    term = st[tag0] + se + et[tags[send * BB + b]];
  } else {
    int startp = pre - lenv;
    if (startp > max_idx) startp = max_idx;
    int endp1 = startp + lenv - 1; if (endp1 > LL - 1) endp1 = LL - 1;
    int sm1 = startp - 1; if (sm1 < 0) sm1 = 0;
    const int  stg = tags[startp * BB + b];
    const int  ptg = tags[sm1 * BB + b];
    const int  etg = tags[endp1 * BB + b];
    const float m  = (float)mask[startp * BB + b];
    const float se = 0.5f * (E[(startp * BB + b) * TT + stg] + E[(endp1 * BB + b) * TT + stg]);
    term = (se + tr[ptg * TT + etg]) * m;
  }
  #pragma unroll
  for (int off = 32; off; off >>= 1) term += __shfl_xor(term, off, 64);
  if (s == 0) atomicAdd(out, term);
}

// ---------------- scan: 1 wave per 16 batches; delay-2 damped normalizer off-path ----------------
__global__ __launch_bounds__(64, 1)
void scan_kernel(const float* __restrict__ tr, const float* __restrict__ st,
                 const float* __restrict__ et, const float* __restrict__ E,
                 const float* __restrict__ ws_, float* __restrict__ out)
{
  const int w = blockIdx.x;      // 0,1 -> batches w*16 .. w*16+15
  const int l = threadIdx.x;
  const int g = l >> 4;
  const int b = w * 16 + (l & 15);
  const char* ws = (const char*)ws_;

  // A = W^T fragments: lane holds A[m=16mb+(l&15)][k=16kb+4g+i], pinned (r2 lesson)
  f16x4 A[3][3];
  #pragma unroll
  for (int mb = 0; mb < 3; ++mb)
    #pragma unroll
    for (int kb = 0; kb < 3; ++kb) {
      f16x4 a;
      #pragma unroll
      for (int i = 0; i < 4; ++i)
        a[i] = (_Float16)__expf(tr[(16 * kb + 4 * g + i) * TT + 16 * mb + (l & 15)]);
      unsigned long long aa = __builtin_bit_cast(unsigned long long, a);
      asm volatile("" : "+v"(aa));
      A[mb][kb] = __builtin_bit_cast(f16x4, aa);
    }

  // init state j=0 (no LDS anywhere in this kernel)
  const float M0 = st[0] + E[b * TT + 0];
  unsigned vd[6]; f16x2 C[6];
  #pragma unroll
  for (int blk = 0; blk < 3; ++blk)
    #pragma unroll
    for (int h = 0; h < 2; ++h) {
      const int t0 = 16 * blk + 4 * g + 2 * h;
      const float ea = E[b * TT + t0], eb = E[b * TT + t0 + 1];
      C[2 * blk + h] = pkrtz(__expf(st[t0] - M0 + 0.5f * ea),
                             __expf(st[t0 + 1] - M0 + 0.5f * eb));
      vd[2 * blk + h] = __builtin_bit_cast(unsigned,
          pkrtz(__expf(st[t0] - M0 + ea), __expf(st[t0 + 1] - M0 + eb)));
    }
  float lsum = 0.f;
  // delay-2 damped normalizer state: eg_j = ENEG * v0_{j-2}^{-1/2}
  // v0_{-1} = v0_0 = 1 exactly (vd[tag0] = exp(0) by construction of M0)
  float bc1   = 1.f;                 // v0_{j-1}
  float lgcur = 0.f;                 // log v0_{j-2} paired with egpk
  f16x2 egpk  = pkrtz(ENEG, ENEG);   // eg for the upcoming step

  // u prefetch ring, depth 8 (slot stride 4096 B); refill via one moving pointer
  const char* Ubase = ws + (size_t)(w * 64 + l) * 32;
  uint4 ua[8], ub[8];
  #pragma unroll
  for (int jj = 1; jj <= 8; ++jj) {
    ua[jj & 7] = *(const uint4*)(Ubase + (size_t)jj * 4096);
    ub[jj & 7] = *(const uint4*)(Ubase + (size_t)jj * 4096 + 16);
  }
  const char* uptr = Ubase + (size_t)9 * 4096;

  const f32x4 zero4 = {0.f, 0.f, 0.f, 0.f};

  auto step = [&](int p) {
    // matvec: 3 independent accumulate-chains on the MFMA pipe
    const f16x4 B0 = mk4(vd[0], vd[1]);
    const f16x4 B1 = mk4(vd[2], vd[3]);
    const f16x4 B2 = mk4(vd[4], vd[5]);
    f32x4 D0 = __builtin_amdgcn_mfma_f32_16x16x16f16(A[0][0], B0, zero4, 0, 0, 0);
    f32x4 D1 = __builtin_amdgcn_mfma_f32_16x16x16f16(A[1][0], B0, zero4, 0, 0, 0);
    f32x4 D2 = __builtin_amdgcn_mfma_f32_16x16x16f16(A[2][0], B0, zero4, 0, 0, 0);
    D0 = __builtin_amdgcn_mfma_f32_16x16x16f16(A[0][1], B1, D0, 0, 0, 0);
    D1 = __builtin_amdgcn_mfma_f32_16x16x16f16(A[1][1], B1, D1, 0, 0, 0);
    D2 = __builtin_amdgcn_mfma_f32_16x16x16f16(A[2][1], B1, D2, 0, 0, 0);
    D0 = __builtin_amdgcn_mfma_f32_16x16x16f16(A[0][2], B2, D0, 0, 0, 0);
    D1 = __builtin_amdgcn_mfma_f32_16x16x16f16(A[1][2], B2, D1, 0, 0, 0);
    D2 = __builtin_amdgcn_mfma_f32_16x16x16f16(A[2][2], B2, D2, 0, 0, 0);

    lsum += 0.5f * lgcur;            // account the eg being applied this step (off-path)

    const uint4 uA = ua[p], uB = ub[p];
    ua[p] = *(const uint4*)uptr;
    ub[p] = *(const uint4*)(uptr + 16);
    uptr += 4096;

    const float mf = __uint_as_float(uB.z);
    const unsigned udw[6] = {uA.x, uA.y, uA.z, uA.w, uB.x, uB.y};
    const float Dv[12] = {D0[0], D0[1], D0[2], D0[3],
                          D1[0], D1[1], D1[2], D1[3],
                          D2[0], D2[1], D2[2], D2[3]};

    if (__builtin_expect(__ballot(mf == 0.f) == 0, 1)) {
      // fast path: Cn = C*eg + pa*(ud*eg), vn = ud*Cn  (pkrtz + mul + pk_fma + mul)
      #pragma unroll
      for (int d6 = 0; d6 < 6; ++d6) {
        const f16x2 ud = __builtin_bit_cast(f16x2, udw[d6]);
        const f16x2 ue = ud * egpk;                 // off-path (egpk ready 1+ step early)
        const f16x2 pa = pkrtz(Dv[2 * d6], Dv[2 * d6 + 1]);
        const f16x2 Cn = C[d6] * egpk + pa * ue;
        C[d6] = Cn;
        vd[d6] = __builtin_bit_cast(unsigned, ud * Cn);
      }
    } else {
      // rare masked path: hold alpha (and C), rescaled
      #pragma unroll
      for (int d6 = 0; d6 < 6; ++d6) {
        const f16x2 ud = __builtin_bit_cast(f16x2, udw[d6]);
        const f16x2 ue = ud * egpk;
        const f16x2 pa = pkrtz(Dv[2 * d6], Dv[2 * d6 + 1]);
        const f16x2 Cn = C[d6] * egpk + pa * ue;
        const f16x2 Ch = C[d6] * egpk;
        const f16x2 vn = ud * Cn;
        const f16x2 vh = __builtin_bit_cast(f16x2, vd[d6]) * egpk;
        const bool keep = (mf > 0.f);
        C[d6] = keep ? Cn : Ch;
        vd[d6] = __builtin_bit_cast(unsigned, keep ? vn : vh);
      }
    }

    // normalizer bookkeeping for step j+1 (all ~2 steps of slack; off critical path)
    const float v0f = (float)__builtin_bit_cast(f16x2, vd[0]).x;   // lanes g==0 hold tag0
    const float v0n = __shfl(v0f, l & 15, 64);                     // per-column broadcast
    const float lg  = __logf(bc1);            // next bc2 = current bc1 = v0_{j-1}
    const float egf = ENEG * __expf(-0.5f * lg);
    egpk  = pkrtz(egf, egf);
    lgcur = lg;
    bc1   = v0n;
  };

  // steps j = 1..511; p = j & 7; refills reach slot 519 (padded)
  for (int c = 0; c < 63; ++c) {
    step(1); step(2); step(3); step(4); step(5); step(6); step(7); step(0);
  }
  step(1); step(2); step(3); step(4); step(5); step(6); step(7);

  // epilogue: denom_b = M0 + 511*GROW + lsum + log(sum_t v[t,b]*exp(et[t]))
  float s = 0.f;
  #pragma unroll
  for (int blk = 0; blk < 3; ++blk)
    #pragma unroll
    for (int h = 0; h < 2; ++h) {
      const int t0 = 16 * blk + 4 * g + 2 * h;
      const f16x2 vp = __builtin_bit_cast(f16x2, vd[2 * blk + h]);
      s += (float)vp.x * __expf(et[t0]) + (float)vp.y * __expf(et[t0 + 1]);
    }
  s += __shfl_xor(s, 16, 64);
  s += __shfl_xor(s, 32, 64);
  float den = (M0 + 511.0f * GROW + lsum) + __logf(s);
  #pragma unroll
  for (int off = 1; off < 16; off <<= 1) den += __shfl_xor(den, off, 64);
  if (l == 0) atomicAdd(out, -den);
}

extern "C" void kernel_launch(void* const* d_in, const int* in_sizes, int n_in,
                              void* d_out, int out_size, void* d_ws, size_t ws_size,
                              hipStream_t stream) {
  (void)in_sizes; (void)n_in; (void)ws_size;
  const float* E    = (const float*)d_in[0];
  const int*   tags = (const int*)d_in[1];
  const int*   lens = (const int*)d_in[2];
  const int*   mask = (const int*)d_in[3];
  const float* st   = (const float*)d_in[4];
  const float* et   = (const float*)d_in[5];
  const float* tr   = (const float*)d_in[6];
  float* out = (float*)d_out;
  (void)hipMemsetAsync(out, 0, out_size * sizeof(float), stream);
  prep_kernel<<<dim3(NSLOT + BB), dim3(128), 0, stream>>>(E, tags, lens, mask, st, et, tr,
                                                          (float*)d_ws, out);
  scan_kernel<<<dim3(2), dim3(64), 0, stream>>>(tr, st, et, E, (const float*)d_ws, out);
}